// Round 7
// baseline (4539.787 us; speedup 1.0000x reference)
//
#include <hip/hip_runtime.h>
#include <math.h>

#define H 16
#define HD 64
#define DDIM 1024
#define LSEQ 1024
#define BATCH 4
#define TOPK 102
#define INV_SCALE 0.125f
#define MROWS (LSEQ * BATCH)   // 4096
#define QKVN (3 * DDIM)        // 3072
#define HBL (H * BATCH * LSEQ) // 65536

// ---------------- fp32 tiled GEMM: C = A(M,K) * B(N,K)^T + bias(N) ----------------
#define BM 128
#define BN 128
#define BKK 16

template <bool PERMUTE>
__global__ __launch_bounds__(256)
void gemm_abT_bias(const float* __restrict__ A, const float* __restrict__ Bw,
                   const float* __restrict__ bias, float* __restrict__ C,
                   int Nd, int Kd) {
    __shared__ float As[BKK][BM + 4];
    __shared__ float Bs[BKK][BN + 4];
    const int tid = threadIdx.x;
    const int tx = tid & 15, ty = tid >> 4;
    const int bn = blockIdx.x * BN, bm = blockIdx.y * BM;
    const int lr = tid >> 1;          // 0..127
    const int lc = (tid & 1) * 8;     // 0 or 8
    const float* Aptr = A + (size_t)(bm + lr) * Kd + lc;
    const float* Bptr = Bw + (size_t)(bn + lr) * Kd + lc;

    float acc[2][2][4][4];
    #pragma unroll
    for (int r = 0; r < 2; ++r)
        #pragma unroll
        for (int c = 0; c < 2; ++c)
            #pragma unroll
            for (int i = 0; i < 4; ++i)
                #pragma unroll
                for (int j = 0; j < 4; ++j) acc[r][c][i][j] = 0.0f;

    float4 av0 = *(const float4*)(Aptr);
    float4 av1 = *(const float4*)(Aptr + 4);
    float4 bv0 = *(const float4*)(Bptr);
    float4 bv1 = *(const float4*)(Bptr + 4);

    for (int k0 = 0; k0 < Kd; k0 += BKK) {
        __syncthreads();
        As[lc + 0][lr] = av0.x; As[lc + 1][lr] = av0.y; As[lc + 2][lr] = av0.z; As[lc + 3][lr] = av0.w;
        As[lc + 4][lr] = av1.x; As[lc + 5][lr] = av1.y; As[lc + 6][lr] = av1.z; As[lc + 7][lr] = av1.w;
        Bs[lc + 0][lr] = bv0.x; Bs[lc + 1][lr] = bv0.y; Bs[lc + 2][lr] = bv0.z; Bs[lc + 3][lr] = bv0.w;
        Bs[lc + 4][lr] = bv1.x; Bs[lc + 5][lr] = bv1.y; Bs[lc + 6][lr] = bv1.z; Bs[lc + 7][lr] = bv1.w;
        __syncthreads();
        if (k0 + BKK < Kd) {
            av0 = *(const float4*)(Aptr + k0 + BKK);
            av1 = *(const float4*)(Aptr + k0 + BKK + 4);
            bv0 = *(const float4*)(Bptr + k0 + BKK);
            bv1 = *(const float4*)(Bptr + k0 + BKK + 4);
        }
        #pragma unroll
        for (int kk = 0; kk < BKK; ++kk) {
            float ar[8], br[8];
            *(float4*)&ar[0] = *(const float4*)&As[kk][ty * 4];
            *(float4*)&ar[4] = *(const float4*)&As[kk][64 + ty * 4];
            *(float4*)&br[0] = *(const float4*)&Bs[kk][tx * 4];
            *(float4*)&br[4] = *(const float4*)&Bs[kk][64 + tx * 4];
            #pragma unroll
            for (int r = 0; r < 2; ++r)
                #pragma unroll
                for (int i = 0; i < 4; ++i)
                    #pragma unroll
                    for (int c = 0; c < 2; ++c)
                        #pragma unroll
                        for (int j = 0; j < 4; ++j)
                            acc[r][c][i][j] += ar[r * 4 + i] * br[c * 4 + j];
        }
    }
    float4 bb[2];
    bb[0] = *(const float4*)&bias[bn + tx * 4];
    bb[1] = *(const float4*)&bias[bn + 64 + tx * 4];
    #pragma unroll
    for (int r = 0; r < 2; ++r)
        #pragma unroll
        for (int i = 0; i < 4; ++i) {
            const int row = bm + r * 64 + ty * 4 + i;
            #pragma unroll
            for (int c = 0; c < 2; ++c) {
                float4 o;
                o.x = acc[r][c][i][0] + bb[c].x;
                o.y = acc[r][c][i][1] + bb[c].y;
                o.z = acc[r][c][i][2] + bb[c].z;
                o.w = acc[r][c][i][3] + bb[c].w;
                if (!PERMUTE) {
                    *(float4*)&C[(size_t)row * Nd + bn + c * 64 + tx * 4] = o;
                } else {
                    const int col = bn + c * 64 + tx * 4;
                    const int which = col >> 10;          // 0=q,1=k,2=v
                    const int hh = (col >> 6) & 15;
                    const int d = col & 63;               // = tx*4
                    const int l = row >> 2, b2 = row & 3; // row = l*B + b
                    float* dst = C + (size_t)which * ((size_t)HBL * HD)
                               + (((size_t)(hh * BATCH + b2) * LSEQ + l) * HD + d);
                    *(float4*)dst = o;
                }
            }
        }
}

// ---------------- fused scores + topk + softmax + sparse PV ----------------
// One block = 4 waves = 4 rows of one (h,b). Score keys live in LDS only.
// launch_bounds(256,2): toolchain budgets 256/2=128 VGPRs (round-5 evidence:
// (256,4)->64), and at 128 VGPR the HW 512-reg pool fits 4 waves/SIMD.
__global__ __launch_bounds__(256, 2)
void fused_attn(const float* __restrict__ Q, const float* __restrict__ K,
                const float* __restrict__ V, const float* __restrict__ S,
                float* __restrict__ attn) {
    __shared__ unsigned sc[4][LSEQ];     // 16 KB  (u32 order-preserving keys)
    __shared__ int      hist[4][256];    // 4 KB   (bucket-swizzled)
    __shared__ float    qs[4][HD];       // 1 KB
    __shared__ int      idxs[4][TOPK];   // 1.6 KB
    __shared__ float    wts[4][TOPK];    // 1.6 KB

    const int h = blockIdx.z, b = blockIdx.y, l0 = blockIdx.x * 4;
    const int tid = threadIdx.x;
    const size_t hb = (size_t)(h * BATCH + b) * LSEQ;

    // Phase A: stage 4 q rows
    if (tid < 64) {
        const int r = tid >> 4, d4 = (tid & 15) * 4;
        *(float4*)&qs[r][d4] = *(const float4*)&Q[(hb + l0 + r) * HD + d4];
    }
    __syncthreads();

    // Phase B: thread handles cols t = tid + j*256 (stride-4B LDS stores,
    // conflict-free; K loads coalesced across lanes). unroll 1: keep the
    // live register set to one j-group so we stay under 128 VGPRs.
    #pragma unroll 1
    for (int j = 0; j < 4; ++j) {
        const int t = tid + j * 256;
        const float* kp = K + (hb + t) * HD;
        float ar[4] = {0.0f, 0.0f, 0.0f, 0.0f};
        #pragma unroll
        for (int dc = 0; dc < 16; ++dc) {
            const float4 kv = *(const float4*)(kp + dc * 4);
            #pragma unroll
            for (int r = 0; r < 4; ++r) {
                const float4 q4 = *(const float4*)&qs[r][dc * 4];
                ar[r] += q4.x * kv.x + q4.y * kv.y + q4.z * kv.z + q4.w * kv.w;
            }
        }
        const float* Scol = S + (size_t)h * DDIM * DDIM + t;
        #pragma unroll
        for (int r = 0; r < 4; ++r) {
            const float v = ar[r] * INV_SCALE + __logf(Scol[(size_t)(l0 + r) * DDIM] + 1e-8f);
            const unsigned bits = __float_as_uint(v);
            sc[r][t] = ((int)bits < 0) ? ~bits : (bits | 0x80000000u);
        }
    }
    __syncthreads();

    // Phase C: per-wave radix select (keys re-read from LDS each pass)
    const int w = tid >> 6, lane = tid & 63;
    const unsigned long long lt = (1ull << lane) - 1ull;
    const unsigned* skey = sc[w];

    unsigned mxu = 0;
    #pragma unroll
    for (int i = 0; i < 16; ++i) {
        const unsigned k = skey[i * 64 + lane];
        mxu = (k > mxu) ? k : mxu;
    }
    #pragma unroll
    for (int off = 32; off; off >>= 1) {
        const unsigned o2 = (unsigned)__shfl_xor((int)mxu, off);
        mxu = (o2 > mxu) ? o2 : mxu;
    }
    const unsigned mbits = (mxu & 0x80000000u) ? (mxu & 0x7fffffffu) : ~mxu;
    const float mxf = __uint_as_float(mbits);

    unsigned prefix = 0, thr = 0;
    int need = TOPK;
    bool early = false;
    for (int pass = 0; pass < 4; ++pass) {
        const int shift = 24 - 8 * pass;
        hist[w][lane] = 0; hist[w][lane + 64] = 0;
        hist[w][lane + 128] = 0; hist[w][lane + 192] = 0;
        #pragma unroll
        for (int i = 0; i < 16; ++i) {
            const unsigned k = skey[i * 64 + lane];
            if (pass == 0 || (k >> (shift + 8)) == prefix) {
                const unsigned bkt = (k >> shift) & 255u;
                atomicAdd(&hist[w][(bkt & 3u) * 64 + (bkt >> 2)], 1);   // swizzled
            }
        }
        // lane owns buckets 4*lane .. 4*lane+3 (each a conflict-free b32 read)
        const int c0 = hist[w][lane];
        const int c1 = hist[w][64 + lane];
        const int c2 = hist[w][128 + lane];
        const int c3 = hist[w][192 + lane];
        int Ssum = c0 + c1 + c2 + c3;
        #pragma unroll
        for (int off = 1; off < 64; off <<= 1) {
            const int t2 = __shfl_down(Ssum, off);
            if (lane + off < 64) Ssum += t2;
        }
        const unsigned long long bal = __ballot(Ssum >= need);
        const int lstar = (int)__popcll(bal) - 1;
        const int above = (lstar < 63) ? __shfl(Ssum, lstar + 1) : 0;
        const int b0 = __shfl(c0, lstar), b1 = __shfl(c1, lstar);
        const int b2 = __shfl(c2, lstar), b3 = __shfl(c3, lstar);
        const int s3 = above + b3, s2 = s3 + b2, s1 = s2 + b1;
        int dstar, cbkt, selab;
        if (s3 >= need)      { dstar = 3; cbkt = b3; selab = above; }
        else if (s2 >= need) { dstar = 2; cbkt = b2; selab = s3; }
        else if (s1 >= need) { dstar = 1; cbkt = b1; selab = s2; }
        else                 { dstar = 0; cbkt = b0; selab = s1; }
        prefix = (prefix << 8) | (unsigned)(lstar * 4 + dstar);
        need -= selab;
        if (cbkt == need) { early = true; thr = prefix << shift; break; }
    }
    if (!early) thr = prefix;   // exact k-th key; `need` ties kept (ascending t)

    // selection + softmax + compaction in one LDS pass (weights unnormalized)
    float lsum = 0.0f;
    int pos = 0, cum = 0;
    #pragma unroll
    for (int i = 0; i < 16; ++i) {
        const unsigned k = skey[i * 64 + lane];
        bool sel;
        if (early) {
            sel = (k >= thr);
        } else {
            const bool eq = (k == thr);
            const unsigned long long em = __ballot(eq);
            const int erank = cum + (int)__popcll(em & lt);
            cum += (int)__popcll(em);
            sel = (k > thr) || (eq && erank < need);
        }
        const unsigned long long sm = __ballot(sel);
        float pe = 0.0f;
        if (sel) {
            const unsigned bits = (k & 0x80000000u) ? (k & 0x7fffffffu) : ~k;
            pe = __expf(__uint_as_float(bits) - mxf);
            const int mypos = pos + (int)__popcll(sm & lt);
            idxs[w][mypos] = i * 64 + lane;
            wts[w][mypos] = pe;
        }
        pos += (int)__popcll(sm);
        lsum += pe;
    }
    #pragma unroll
    for (int off = 32; off; off >>= 1) lsum += __shfl_xor(lsum, off);
    const float inv = 1.0f / lsum;

    // Phase D: sparse PV (lane = d); normalize at the end
    const float* vb = V + hb * HD + lane;
    float o0 = 0.0f, o1 = 0.0f;
    for (int j = 0; j < TOPK; j += 2) {
        const int2 ii = *(const int2*)&idxs[w][j];
        const float2 ww = *(const float2*)&wts[w][j];
        o0 += ww.x * vb[(size_t)ii.x * HD];
        o1 += ww.y * vb[(size_t)ii.y * HD];
    }
    attn[((size_t)(l0 + w) * BATCH + b) * DDIM + h * HD + lane] = (o0 + o1) * inv;
}

// ---------------- launcher ----------------
extern "C" void kernel_launch(void* const* d_in, const int* in_sizes, int n_in,
                              void* d_out, int out_size, void* d_ws, size_t ws_size,
                              hipStream_t stream) {
    (void)in_sizes; (void)n_in; (void)out_size; (void)ws_size;
    const float* x      = (const float*)d_in[0];
    const float* qkv_w  = (const float*)d_in[1];
    const float* qkv_b  = (const float*)d_in[2];
    const float* out_w  = (const float*)d_in[3];
    const float* out_b  = (const float*)d_in[4];
    const float* S      = (const float*)d_in[5];
    float* out = (float*)d_out;

    // workspace: Q|K|V (each HBL x 64) + attn (L*B x D)  = 67 MB total
    float* Q    = (float*)d_ws;
    float* Kb   = Q + (size_t)HBL * HD;
    float* V    = Kb + (size_t)HBL * HD;
    float* attn = V + (size_t)HBL * HD;

    // K1: qkv = x @ qkv_w^T + qkv_b, scattered into Q/K/V (H,B,L,64)
    gemm_abT_bias<true><<<dim3(QKVN / BN, MROWS / BM), 256, 0, stream>>>(
        x, qkv_w, qkv_b, Q, QKVN, DDIM);

    // K2: fused scores + topk + softmax + sparse PV
    fused_attn<<<dim3(LSEQ / 4, BATCH, H), 256, 0, stream>>>(Q, Kb, V, S, attn);

    // K3: out = attn @ out_w^T + out_b
    gemm_abT_bias<false><<<dim3(DDIM / BN, MROWS / BM), 256, 0, stream>>>(
        attn, out_w, out_b, out, DDIM, DDIM);
}

// Round 8
// 1070.136 us; speedup vs baseline: 4.2423x; 4.2423x over previous
//
#include <hip/hip_runtime.h>
#include <math.h>

#define H 16
#define HD 64
#define DDIM 1024
#define LSEQ 1024
#define BATCH 4
#define TOPK 102
#define INV_SCALE 0.125f
#define MROWS (LSEQ * BATCH)   // 4096
#define QKVN (3 * DDIM)        // 3072
#define HBL (H * BATCH * LSEQ) // 65536
#define RPB 8                  // rows per block (1 row per wave)

// ---------------- fp32 tiled GEMM: C = A(M,K) * B(N,K)^T + bias(N) ----------------
#define BM 128
#define BN 128
#define BKK 16

template <bool PERMUTE>
__global__ __launch_bounds__(256)
void gemm_abT_bias(const float* __restrict__ A, const float* __restrict__ Bw,
                   const float* __restrict__ bias, float* __restrict__ C,
                   int Nd, int Kd) {
    __shared__ float As[BKK][BM + 4];
    __shared__ float Bs[BKK][BN + 4];
    const int tid = threadIdx.x;
    const int tx = tid & 15, ty = tid >> 4;
    const int bn = blockIdx.x * BN, bm = blockIdx.y * BM;
    const int lr = tid >> 1;          // 0..127
    const int lc = (tid & 1) * 8;     // 0 or 8
    const float* Aptr = A + (size_t)(bm + lr) * Kd + lc;
    const float* Bptr = Bw + (size_t)(bn + lr) * Kd + lc;

    float acc[2][2][4][4];
    #pragma unroll
    for (int r = 0; r < 2; ++r)
        #pragma unroll
        for (int c = 0; c < 2; ++c)
            #pragma unroll
            for (int i = 0; i < 4; ++i)
                #pragma unroll
                for (int j = 0; j < 4; ++j) acc[r][c][i][j] = 0.0f;

    float4 av0 = *(const float4*)(Aptr);
    float4 av1 = *(const float4*)(Aptr + 4);
    float4 bv0 = *(const float4*)(Bptr);
    float4 bv1 = *(const float4*)(Bptr + 4);

    for (int k0 = 0; k0 < Kd; k0 += BKK) {
        __syncthreads();
        As[lc + 0][lr] = av0.x; As[lc + 1][lr] = av0.y; As[lc + 2][lr] = av0.z; As[lc + 3][lr] = av0.w;
        As[lc + 4][lr] = av1.x; As[lc + 5][lr] = av1.y; As[lc + 6][lr] = av1.z; As[lc + 7][lr] = av1.w;
        Bs[lc + 0][lr] = bv0.x; Bs[lc + 1][lr] = bv0.y; Bs[lc + 2][lr] = bv0.z; Bs[lc + 3][lr] = bv0.w;
        Bs[lc + 4][lr] = bv1.x; Bs[lc + 5][lr] = bv1.y; Bs[lc + 6][lr] = bv1.z; Bs[lc + 7][lr] = bv1.w;
        __syncthreads();
        if (k0 + BKK < Kd) {
            av0 = *(const float4*)(Aptr + k0 + BKK);
            av1 = *(const float4*)(Aptr + k0 + BKK + 4);
            bv0 = *(const float4*)(Bptr + k0 + BKK);
            bv1 = *(const float4*)(Bptr + k0 + BKK + 4);
        }
        #pragma unroll
        for (int kk = 0; kk < BKK; ++kk) {
            float ar[8], br[8];
            *(float4*)&ar[0] = *(const float4*)&As[kk][ty * 4];
            *(float4*)&ar[4] = *(const float4*)&As[kk][64 + ty * 4];
            *(float4*)&br[0] = *(const float4*)&Bs[kk][tx * 4];
            *(float4*)&br[4] = *(const float4*)&Bs[kk][64 + tx * 4];
            #pragma unroll
            for (int r = 0; r < 2; ++r)
                #pragma unroll
                for (int i = 0; i < 4; ++i)
                    #pragma unroll
                    for (int c = 0; c < 2; ++c)
                        #pragma unroll
                        for (int j = 0; j < 4; ++j)
                            acc[r][c][i][j] += ar[r * 4 + i] * br[c * 4 + j];
        }
    }
    float4 bb[2];
    bb[0] = *(const float4*)&bias[bn + tx * 4];
    bb[1] = *(const float4*)&bias[bn + 64 + tx * 4];
    #pragma unroll
    for (int r = 0; r < 2; ++r)
        #pragma unroll
        for (int i = 0; i < 4; ++i) {
            const int row = bm + r * 64 + ty * 4 + i;
            #pragma unroll
            for (int c = 0; c < 2; ++c) {
                float4 o;
                o.x = acc[r][c][i][0] + bb[c].x;
                o.y = acc[r][c][i][1] + bb[c].y;
                o.z = acc[r][c][i][2] + bb[c].z;
                o.w = acc[r][c][i][3] + bb[c].w;
                if (!PERMUTE) {
                    *(float4*)&C[(size_t)row * Nd + bn + c * 64 + tx * 4] = o;
                } else {
                    const int col = bn + c * 64 + tx * 4;
                    const int which = col >> 10;          // 0=q,1=k,2=v
                    const int hh = (col >> 6) & 15;
                    const int d = col & 63;               // = tx*4
                    const int l = row >> 2, b2 = row & 3; // row = l*B + b
                    float* dst = C + (size_t)which * ((size_t)HBL * HD)
                               + (((size_t)(hh * BATCH + b2) * LSEQ + l) * HD + d);
                    *(float4*)dst = o;
                }
            }
        }
}

// ---------------- fused scores + topk + softmax + sparse PV ----------------
// One block = 8 waves = 8 rows of one (h,b); one row per wave in the select
// phase. Score keys live in LDS only. Natural register allocation (no caps —
// round-7 lesson: forcing below the live set causes GB-scale spills).
__global__ __launch_bounds__(512)
void fused_attn(const float* __restrict__ Q, const float* __restrict__ K,
                const float* __restrict__ V, const float* __restrict__ S,
                float* __restrict__ attn) {
    __shared__ unsigned sc[RPB][LSEQ];     // 32 KB (u32 order-preserving keys)
    __shared__ int      hist[RPB][256];    // 8 KB  (bucket-swizzled)
    __shared__ float    qs[RPB][HD];       // 2 KB
    __shared__ int      idxs[RPB][TOPK];   // 3.2 KB
    __shared__ float    wts[RPB][TOPK];    // 3.2 KB

    const int h = blockIdx.z, b = blockIdx.y, l0 = blockIdx.x * RPB;
    const int tid = threadIdx.x;
    const size_t hb = (size_t)(h * BATCH + b) * LSEQ;

    // Phase A: stage 8 q rows
    if (tid < 128) {
        const int r = tid >> 4, d4 = (tid & 15) * 4;
        *(float4*)&qs[r][d4] = *(const float4*)&Q[(hb + l0 + r) * HD + d4];
    }
    __syncthreads();

    // Phase B: thread handles cols t = tid + j*512 (stride-4B LDS stores,
    // conflict-free; K loads coalesced). j rolled + dc unroll 8 keeps the
    // live register set ~<=8 float4 K values.
    #pragma unroll 1
    for (int j = 0; j < 2; ++j) {
        const int t = tid + j * 512;
        const float* kp = K + (hb + t) * HD;
        float ar[RPB];
        #pragma unroll
        for (int r = 0; r < RPB; ++r) ar[r] = 0.0f;
        #pragma unroll 8
        for (int dc = 0; dc < 16; ++dc) {
            const float4 kv = *(const float4*)(kp + dc * 4);
            #pragma unroll
            for (int r = 0; r < RPB; ++r) {
                const float4 q4 = *(const float4*)&qs[r][dc * 4];
                ar[r] += q4.x * kv.x + q4.y * kv.y + q4.z * kv.z + q4.w * kv.w;
            }
        }
        const float* Srow = S + (size_t)h * DDIM * DDIM + t;
        #pragma unroll
        for (int r = 0; r < RPB; ++r) {
            const float v = ar[r] * INV_SCALE + __logf(Srow[(size_t)(l0 + r) * DDIM] + 1e-8f);
            const unsigned bits = __float_as_uint(v);
            sc[r][t] = ((int)bits < 0) ? ~bits : (bits | 0x80000000u);
        }
    }
    __syncthreads();

    // Phase C: per-wave radix select; wave w owns row w (keys re-read from LDS)
    const int w = tid >> 6, lane = tid & 63;
    const unsigned long long lt = (1ull << lane) - 1ull;
    const unsigned* skey = sc[w];

    unsigned mxu = 0;
    #pragma unroll
    for (int i = 0; i < 16; ++i) {
        const unsigned k = skey[i * 64 + lane];
        mxu = (k > mxu) ? k : mxu;
    }
    #pragma unroll
    for (int off = 32; off; off >>= 1) {
        const unsigned o2 = (unsigned)__shfl_xor((int)mxu, off);
        mxu = (o2 > mxu) ? o2 : mxu;
    }
    const unsigned mbits = (mxu & 0x80000000u) ? (mxu & 0x7fffffffu) : ~mxu;
    const float mxf = __uint_as_float(mbits);

    unsigned prefix = 0, thr = 0;
    int need = TOPK;
    bool early = false;
    for (int pass = 0; pass < 4; ++pass) {
        const int shift = 24 - 8 * pass;
        hist[w][lane] = 0; hist[w][lane + 64] = 0;
        hist[w][lane + 128] = 0; hist[w][lane + 192] = 0;
        #pragma unroll
        for (int i = 0; i < 16; ++i) {
            const unsigned k = skey[i * 64 + lane];
            if (pass == 0 || (k >> (shift + 8)) == prefix) {
                const unsigned bkt = (k >> shift) & 255u;
                atomicAdd(&hist[w][(bkt & 3u) * 64 + (bkt >> 2)], 1);   // swizzled
            }
        }
        // lane owns buckets 4*lane .. 4*lane+3 (conflict-free b32 reads)
        const int c0 = hist[w][lane];
        const int c1 = hist[w][64 + lane];
        const int c2 = hist[w][128 + lane];
        const int c3 = hist[w][192 + lane];
        int Ssum = c0 + c1 + c2 + c3;
        #pragma unroll
        for (int off = 1; off < 64; off <<= 1) {
            const int t2 = __shfl_down(Ssum, off);
            if (lane + off < 64) Ssum += t2;
        }
        const unsigned long long bal = __ballot(Ssum >= need);
        const int lstar = (int)__popcll(bal) - 1;
        const int above = (lstar < 63) ? __shfl(Ssum, lstar + 1) : 0;
        const int b0 = __shfl(c0, lstar), b1 = __shfl(c1, lstar);
        const int b2 = __shfl(c2, lstar), b3 = __shfl(c3, lstar);
        const int s3 = above + b3, s2 = s3 + b2, s1 = s2 + b1;
        int dstar, cbkt, selab;
        if (s3 >= need)      { dstar = 3; cbkt = b3; selab = above; }
        else if (s2 >= need) { dstar = 2; cbkt = b2; selab = s3; }
        else if (s1 >= need) { dstar = 1; cbkt = b1; selab = s2; }
        else                 { dstar = 0; cbkt = b0; selab = s1; }
        prefix = (prefix << 8) | (unsigned)(lstar * 4 + dstar);
        need -= selab;
        if (cbkt == need) { early = true; thr = prefix << shift; break; }
    }
    if (!early) thr = prefix;   // exact k-th key; `need` ties kept (ascending t)

    // selection + softmax + compaction in one LDS pass (weights unnormalized)
    float lsum = 0.0f;
    int pos = 0, cum = 0;
    #pragma unroll
    for (int i = 0; i < 16; ++i) {
        const unsigned k = skey[i * 64 + lane];
        bool sel;
        if (early) {
            sel = (k >= thr);
        } else {
            const bool eq = (k == thr);
            const unsigned long long em = __ballot(eq);
            const int erank = cum + (int)__popcll(em & lt);
            cum += (int)__popcll(em);
            sel = (k > thr) || (eq && erank < need);
        }
        const unsigned long long sm = __ballot(sel);
        float pe = 0.0f;
        if (sel) {
            const unsigned bits = (k & 0x80000000u) ? (k & 0x7fffffffu) : ~k;
            pe = __expf(__uint_as_float(bits) - mxf);
            const int mypos = pos + (int)__popcll(sm & lt);
            idxs[w][mypos] = i * 64 + lane;
            wts[w][mypos] = pe;
        }
        pos += (int)__popcll(sm);
        lsum += pe;
    }
    #pragma unroll
    for (int off = 32; off; off >>= 1) lsum += __shfl_xor(lsum, off);
    const float inv = 1.0f / lsum;

    // Phase D: sparse PV (lane = d); normalize at the end
    const float* vb = V + hb * HD + lane;
    float o0 = 0.0f, o1 = 0.0f;
    for (int j = 0; j < TOPK; j += 2) {
        const int2 ii = *(const int2*)&idxs[w][j];
        const float2 ww = *(const float2*)&wts[w][j];
        o0 += ww.x * vb[(size_t)ii.x * HD];
        o1 += ww.y * vb[(size_t)ii.y * HD];
    }
    attn[((size_t)(l0 + w) * BATCH + b) * DDIM + h * HD + lane] = (o0 + o1) * inv;
}

// ---------------- launcher ----------------
extern "C" void kernel_launch(void* const* d_in, const int* in_sizes, int n_in,
                              void* d_out, int out_size, void* d_ws, size_t ws_size,
                              hipStream_t stream) {
    (void)in_sizes; (void)n_in; (void)out_size; (void)ws_size;
    const float* x      = (const float*)d_in[0];
    const float* qkv_w  = (const float*)d_in[1];
    const float* qkv_b  = (const float*)d_in[2];
    const float* out_w  = (const float*)d_in[3];
    const float* out_b  = (const float*)d_in[4];
    const float* S      = (const float*)d_in[5];
    float* out = (float*)d_out;

    // workspace: Q|K|V (each HBL x 64) + attn (L*B x D)  = 67 MB total
    float* Q    = (float*)d_ws;
    float* Kb   = Q + (size_t)HBL * HD;
    float* V    = Kb + (size_t)HBL * HD;
    float* attn = V + (size_t)HBL * HD;

    // K1: qkv = x @ qkv_w^T + qkv_b, scattered into Q/K/V (H,B,L,64)
    gemm_abT_bias<true><<<dim3(QKVN / BN, MROWS / BM), 256, 0, stream>>>(
        x, qkv_w, qkv_b, Q, QKVN, DDIM);

    // K2: fused scores + topk + softmax + sparse PV
    fused_attn<<<dim3(LSEQ / RPB, BATCH, H), 512, 0, stream>>>(Q, Kb, V, S, attn);

    // K3: out = attn @ out_w^T + out_b
    gemm_abT_bias<false><<<dim3(DDIM / BN, MROWS / BM), 256, 0, stream>>>(
        attn, out_w, out_b, out, DDIM, DDIM);
}

// Round 10
// 1003.455 us; speedup vs baseline: 4.5242x; 1.0665x over previous
//
#include <hip/hip_runtime.h>
#include <math.h>

#define H 16
#define HD 64
#define DDIM 1024
#define LSEQ 1024
#define BATCH 4
#define TOPK 102
#define INV_SCALE 0.125f
#define MROWS (LSEQ * BATCH)   // 4096
#define QKVN (3 * DDIM)        // 3072
#define HBL (H * BATCH * LSEQ) // 65536
#define RPB 8                  // rows per block in fused_attn

typedef __attribute__((ext_vector_type(8))) short bf16x8;
typedef __attribute__((ext_vector_type(4))) float f32x4;

__device__ __forceinline__ unsigned short f2bf(float f) {
    unsigned u = __float_as_uint(f);
    u += 0x7FFFu + ((u >> 16) & 1u);
    return (unsigned short)(u >> 16);
}
__device__ __forceinline__ float bf2f(unsigned short h) {
    return __uint_as_float(((unsigned)h) << 16);
}

// ---------------- fp32 -> bf16 2-way split (hi/lo) ----------------
__global__ __launch_bounds__(256)
void split_bf16(const float* __restrict__ src, unsigned short* __restrict__ dh,
                unsigned short* __restrict__ dl, int n4) {
    for (int i = blockIdx.x * 256 + threadIdx.x; i < n4; i += gridDim.x * 256) {
        const float4 v = ((const float4*)src)[i];
        ushort4 h, l;
        h.x = f2bf(v.x); l.x = f2bf(v.x - bf2f(h.x));
        h.y = f2bf(v.y); l.y = f2bf(v.y - bf2f(h.y));
        h.z = f2bf(v.z); l.z = f2bf(v.z - bf2f(h.z));
        h.w = f2bf(v.w); l.w = f2bf(v.w - bf2f(h.w));
        ((ushort4*)dh)[i] = h;
        ((ushort4*)dl)[i] = l;
    }
}

// ---------------- fp32 -> bf16 3-way split (hi/lo/mid: 24 mantissa bits) ----------------
__global__ __launch_bounds__(256)
void split3_bf16(const float* __restrict__ src, unsigned short* __restrict__ dh,
                 unsigned short* __restrict__ dl, unsigned short* __restrict__ dm, int n4) {
    for (int i = blockIdx.x * 256 + threadIdx.x; i < n4; i += gridDim.x * 256) {
        const float4 v = ((const float4*)src)[i];
        ushort4 h, l, m;
        float r;
        h.x = f2bf(v.x); r = v.x - bf2f(h.x); l.x = f2bf(r); m.x = f2bf(r - bf2f(l.x));
        h.y = f2bf(v.y); r = v.y - bf2f(h.y); l.y = f2bf(r); m.y = f2bf(r - bf2f(l.y));
        h.z = f2bf(v.z); r = v.z - bf2f(h.z); l.z = f2bf(r); m.z = f2bf(r - bf2f(l.z));
        h.w = f2bf(v.w); r = v.w - bf2f(h.w); l.w = f2bf(r); m.w = f2bf(r - bf2f(l.w));
        ((ushort4*)dh)[i] = h;
        ((ushort4*)dl)[i] = l;
        ((ushort4*)dm)[i] = m;
    }
}

// ---------------- bf16x3-split MFMA GEMM (6 products, fp32-exact to ~2^-26) ----------
// C = A(M,K) * B(N,K)^T + bias. Used for the QKV projection, where score
// fidelity matters: topk selection flips need score error << adjacent-gap.
// Block 256 = 4 waves, tile 128x128, wave 64x64 (4x4 frags of 16x16x32).
template <bool PERMUTE>
__global__ __launch_bounds__(256)
void gemm_bf16x3(const unsigned short* __restrict__ Ah, const unsigned short* __restrict__ Al,
                 const unsigned short* __restrict__ Am,
                 const unsigned short* __restrict__ Bh, const unsigned short* __restrict__ Bl,
                 const unsigned short* __restrict__ Bm,
                 const float* __restrict__ bias, float* __restrict__ C,
                 int Nd, int Kd) {
    const int tid = threadIdx.x;
    const int w = tid >> 6, lane = tid & 63;
    const int bmt = blockIdx.y * 128, bnt = blockIdx.x * 128;
    const int wm = (w >> 1) * 64, wn = (w & 1) * 64;
    const int r16 = lane & 15, ch = lane >> 4;

    const size_t arow0 = (size_t)(bmt + wm + r16);
    const size_t brow0 = (size_t)(bnt + wn + r16);

    f32x4 acc[4][4] = {};

    for (int k0 = 0; k0 < Kd; k0 += 32) {
        const size_t koff = (size_t)k0 + ch * 8;
        bf16x8 ah[4], al[4], am[4];
        #pragma unroll
        for (int i = 0; i < 4; ++i) {
            const size_t ao = (arow0 + i * 16) * Kd + koff;
            ah[i] = *(const bf16x8*)(Ah + ao);
            al[i] = *(const bf16x8*)(Al + ao);
            am[i] = *(const bf16x8*)(Am + ao);
        }
        #pragma unroll
        for (int j = 0; j < 4; ++j) {
            const size_t bo = (brow0 + j * 16) * Kd + koff;
            const bf16x8 bh = *(const bf16x8*)(Bh + bo);
            const bf16x8 bl = *(const bf16x8*)(Bl + bo);
            const bf16x8 bm8 = *(const bf16x8*)(Bm + bo);
            #pragma unroll
            for (int i = 0; i < 4; ++i) {
                acc[i][j] = __builtin_amdgcn_mfma_f32_16x16x32_bf16(ah[i], bh, acc[i][j], 0, 0, 0);
                acc[i][j] = __builtin_amdgcn_mfma_f32_16x16x32_bf16(ah[i], bl, acc[i][j], 0, 0, 0);
                acc[i][j] = __builtin_amdgcn_mfma_f32_16x16x32_bf16(al[i], bh, acc[i][j], 0, 0, 0);
                acc[i][j] = __builtin_amdgcn_mfma_f32_16x16x32_bf16(al[i], bl, acc[i][j], 0, 0, 0);
                acc[i][j] = __builtin_amdgcn_mfma_f32_16x16x32_bf16(ah[i], bm8, acc[i][j], 0, 0, 0);
                acc[i][j] = __builtin_amdgcn_mfma_f32_16x16x32_bf16(am[i], bh, acc[i][j], 0, 0, 0);
            }
        }
    }

    float bj[4];
    #pragma unroll
    for (int j = 0; j < 4; ++j) bj[j] = bias[bnt + wn + j * 16 + r16];

    // C/D frag layout: col = lane&15, row = (lane>>4)*4 + reg
    #pragma unroll
    for (int i = 0; i < 4; ++i) {
        #pragma unroll
        for (int r = 0; r < 4; ++r) {
            const int R = bmt + wm + i * 16 + ch * 4 + r;
            #pragma unroll
            for (int j = 0; j < 4; ++j) {
                const float v = acc[i][j][r] + bj[j];
                const int Cc = bnt + wn + j * 16 + r16;
                if (!PERMUTE) {
                    C[(size_t)R * Nd + Cc] = v;
                } else {
                    const int which = Cc >> 10, hh = (Cc >> 6) & 15, d = Cc & 63;
                    const int l = R >> 2, b2 = R & 3;
                    C[(size_t)which * ((size_t)HBL * HD)
                      + (((size_t)(hh * BATCH + b2) * LSEQ + l) * HD + d)] = v;
                }
            }
        }
    }
}

// ---------------- bf16x2-split MFMA GEMM (3 products) ----------------
// Used for the output projection (no discrete selection downstream;
// ~2^-17 relative error is invisible vs the 4.6e-3 threshold).
template <bool PERMUTE>
__global__ __launch_bounds__(256)
void gemm_bf16x2(const unsigned short* __restrict__ Ah, const unsigned short* __restrict__ Al,
                 const unsigned short* __restrict__ Bh, const unsigned short* __restrict__ Bl,
                 const float* __restrict__ bias, float* __restrict__ C,
                 int Nd, int Kd) {
    const int tid = threadIdx.x;
    const int w = tid >> 6, lane = tid & 63;
    const int bmt = blockIdx.y * 128, bnt = blockIdx.x * 128;
    const int wm = (w >> 1) * 64, wn = (w & 1) * 64;
    const int r16 = lane & 15, ch = lane >> 4;

    const size_t arow0 = (size_t)(bmt + wm + r16);
    const size_t brow0 = (size_t)(bnt + wn + r16);

    f32x4 acc[4][4] = {};

    for (int k0 = 0; k0 < Kd; k0 += 32) {
        const size_t koff = (size_t)k0 + ch * 8;
        bf16x8 ah[4], al[4], bh[4], bl[4];
        #pragma unroll
        for (int i = 0; i < 4; ++i) {
            const size_t ao = (arow0 + i * 16) * Kd + koff;
            ah[i] = *(const bf16x8*)(Ah + ao);
            al[i] = *(const bf16x8*)(Al + ao);
            const size_t bo = (brow0 + i * 16) * Kd + koff;
            bh[i] = *(const bf16x8*)(Bh + bo);
            bl[i] = *(const bf16x8*)(Bl + bo);
        }
        #pragma unroll
        for (int i = 0; i < 4; ++i)
            #pragma unroll
            for (int j = 0; j < 4; ++j) {
                acc[i][j] = __builtin_amdgcn_mfma_f32_16x16x32_bf16(ah[i], bh[j], acc[i][j], 0, 0, 0);
                acc[i][j] = __builtin_amdgcn_mfma_f32_16x16x32_bf16(ah[i], bl[j], acc[i][j], 0, 0, 0);
                acc[i][j] = __builtin_amdgcn_mfma_f32_16x16x32_bf16(al[i], bh[j], acc[i][j], 0, 0, 0);
            }
    }

    float bj[4];
    #pragma unroll
    for (int j = 0; j < 4; ++j) bj[j] = bias[bnt + wn + j * 16 + r16];

    #pragma unroll
    for (int i = 0; i < 4; ++i) {
        #pragma unroll
        for (int r = 0; r < 4; ++r) {
            const int R = bmt + wm + i * 16 + ch * 4 + r;
            #pragma unroll
            for (int j = 0; j < 4; ++j) {
                const float v = acc[i][j][r] + bj[j];
                const int Cc = bnt + wn + j * 16 + r16;
                if (!PERMUTE) {
                    C[(size_t)R * Nd + Cc] = v;
                } else {
                    const int which = Cc >> 10, hh = (Cc >> 6) & 15, d = Cc & 63;
                    const int l = R >> 2, b2 = R & 3;
                    C[(size_t)which * ((size_t)HBL * HD)
                      + (((size_t)(hh * BATCH + b2) * LSEQ + l) * HD + d)] = v;
                }
            }
        }
    }
}

// ---------------- fused scores + topk + softmax + sparse PV ----------------
// One block = 8 waves = 8 rows of one (h,b); one row per wave. Keys in LDS.
// Emits attn as bf16 hi/lo for the MFMA output projection.
__global__ __launch_bounds__(512)
void fused_attn(const float* __restrict__ Q, const float* __restrict__ K,
                const float* __restrict__ V, const float* __restrict__ S,
                unsigned short* __restrict__ attn_h, unsigned short* __restrict__ attn_l) {
    __shared__ unsigned sc[RPB][LSEQ];     // 32 KB (u32 order-preserving keys)
    __shared__ int      hist[RPB][256];    // 8 KB  (bucket-swizzled)
    __shared__ float    qs[RPB][HD];       // 2 KB
    __shared__ int      idxs[RPB][TOPK];   // 3.2 KB
    __shared__ float    wts[RPB][TOPK];    // 3.2 KB

    const int h = blockIdx.z, b = blockIdx.y, l0 = blockIdx.x * RPB;
    const int tid = threadIdx.x;
    const size_t hb = (size_t)(h * BATCH + b) * LSEQ;

    if (tid < 128) {
        const int r = tid >> 4, d4 = (tid & 15) * 4;
        *(float4*)&qs[r][d4] = *(const float4*)&Q[(hb + l0 + r) * HD + d4];
    }
    __syncthreads();

    #pragma unroll 1
    for (int j = 0; j < 2; ++j) {
        const int t = tid + j * 512;
        const float* kp = K + (hb + t) * HD;
        float ar[RPB];
        #pragma unroll
        for (int r = 0; r < RPB; ++r) ar[r] = 0.0f;
        #pragma unroll 8
        for (int dc = 0; dc < 16; ++dc) {
            const float4 kv = *(const float4*)(kp + dc * 4);
            #pragma unroll
            for (int r = 0; r < RPB; ++r) {
                const float4 q4 = *(const float4*)&qs[r][dc * 4];
                ar[r] += q4.x * kv.x + q4.y * kv.y + q4.z * kv.z + q4.w * kv.w;
            }
        }
        const float* Srow = S + (size_t)h * DDIM * DDIM + t;
        #pragma unroll
        for (int r = 0; r < RPB; ++r) {
            const float v = ar[r] * INV_SCALE + __logf(Srow[(size_t)(l0 + r) * DDIM] + 1e-8f);
            const unsigned bits = __float_as_uint(v);
            sc[r][t] = ((int)bits < 0) ? ~bits : (bits | 0x80000000u);
        }
    }
    __syncthreads();

    const int w = tid >> 6, lane = tid & 63;
    const unsigned long long lt = (1ull << lane) - 1ull;
    const unsigned* skey = sc[w];

    unsigned mxu = 0;
    #pragma unroll
    for (int i = 0; i < 16; ++i) {
        const unsigned k = skey[i * 64 + lane];
        mxu = (k > mxu) ? k : mxu;
    }
    #pragma unroll
    for (int off = 32; off; off >>= 1) {
        const unsigned o2 = (unsigned)__shfl_xor((int)mxu, off);
        mxu = (o2 > mxu) ? o2 : mxu;
    }
    const unsigned mbits = (mxu & 0x80000000u) ? (mxu & 0x7fffffffu) : ~mxu;
    const float mxf = __uint_as_float(mbits);

    unsigned prefix = 0, thr = 0;
    int need = TOPK;
    bool early = false;
    for (int pass = 0; pass < 4; ++pass) {
        const int shift = 24 - 8 * pass;
        hist[w][lane] = 0; hist[w][lane + 64] = 0;
        hist[w][lane + 128] = 0; hist[w][lane + 192] = 0;
        #pragma unroll
        for (int i = 0; i < 16; ++i) {
            const unsigned k = skey[i * 64 + lane];
            if (pass == 0 || (k >> (shift + 8)) == prefix) {
                const unsigned bkt = (k >> shift) & 255u;
                atomicAdd(&hist[w][(bkt & 3u) * 64 + (bkt >> 2)], 1);   // swizzled
            }
        }
        const int c0 = hist[w][lane];
        const int c1 = hist[w][64 + lane];
        const int c2 = hist[w][128 + lane];
        const int c3 = hist[w][192 + lane];
        int Ssum = c0 + c1 + c2 + c3;
        #pragma unroll
        for (int off = 1; off < 64; off <<= 1) {
            const int t2 = __shfl_down(Ssum, off);
            if (lane + off < 64) Ssum += t2;
        }
        const unsigned long long bal = __ballot(Ssum >= need);
        const int lstar = (int)__popcll(bal) - 1;
        const int above = (lstar < 63) ? __shfl(Ssum, lstar + 1) : 0;
        const int b0 = __shfl(c0, lstar), b1 = __shfl(c1, lstar);
        const int b2 = __shfl(c2, lstar), b3 = __shfl(c3, lstar);
        const int s3 = above + b3, s2 = s3 + b2, s1 = s2 + b1;
        int dstar, cbkt, selab;
        if (s3 >= need)      { dstar = 3; cbkt = b3; selab = above; }
        else if (s2 >= need) { dstar = 2; cbkt = b2; selab = s3; }
        else if (s1 >= need) { dstar = 1; cbkt = b1; selab = s2; }
        else                 { dstar = 0; cbkt = b0; selab = s1; }
        prefix = (prefix << 8) | (unsigned)(lstar * 4 + dstar);
        need -= selab;
        if (cbkt == need) { early = true; thr = prefix << shift; break; }
    }
    if (!early) thr = prefix;   // exact k-th key; `need` ties kept (ascending t)

    float lsum = 0.0f;
    int pos = 0, cum = 0;
    #pragma unroll
    for (int i = 0; i < 16; ++i) {
        const unsigned k = skey[i * 64 + lane];
        bool sel;
        if (early) {
            sel = (k >= thr);
        } else {
            const bool eq = (k == thr);
            const unsigned long long em = __ballot(eq);
            const int erank = cum + (int)__popcll(em & lt);
            cum += (int)__popcll(em);
            sel = (k > thr) || (eq && erank < need);
        }
        const unsigned long long sm = __ballot(sel);
        float pe = 0.0f;
        if (sel) {
            const unsigned bits = (k & 0x80000000u) ? (k & 0x7fffffffu) : ~k;
            pe = __expf(__uint_as_float(bits) - mxf);
            const int mypos = pos + (int)__popcll(sm & lt);
            idxs[w][mypos] = i * 64 + lane;
            wts[w][mypos] = pe;
        }
        pos += (int)__popcll(sm);
        lsum += pe;
    }
    #pragma unroll
    for (int off = 32; off; off >>= 1) lsum += __shfl_xor(lsum, off);
    const float inv = 1.0f / lsum;

    const float* vb = V + hb * HD + lane;
    float o0 = 0.0f, o1 = 0.0f;
    for (int j = 0; j < TOPK; j += 2) {
        const int2 ii = *(const int2*)&idxs[w][j];
        const float2 ww = *(const float2*)&wts[w][j];
        o0 += ww.x * vb[(size_t)ii.x * HD];
        o1 += ww.y * vb[(size_t)ii.y * HD];
    }
    const float o = (o0 + o1) * inv;
    const size_t oidx = ((size_t)(l0 + w) * BATCH + b) * DDIM + h * HD + lane;
    const unsigned short hbits = f2bf(o);
    attn_h[oidx] = hbits;
    attn_l[oidx] = f2bf(o - bf2f(hbits));
}

// ---------------- launcher ----------------
extern "C" void kernel_launch(void* const* d_in, const int* in_sizes, int n_in,
                              void* d_out, int out_size, void* d_ws, size_t ws_size,
                              hipStream_t stream) {
    (void)in_sizes; (void)n_in; (void)out_size; (void)ws_size;
    const float* x      = (const float*)d_in[0];
    const float* qkv_w  = (const float*)d_in[1];
    const float* qkv_b  = (const float*)d_in[2];
    const float* out_w  = (const float*)d_in[3];
    const float* out_b  = (const float*)d_in[4];
    const float* S      = (const float*)d_in[5];
    float* out = (float*)d_out;

    // workspace (~94 MB peak):
    //   Q|K|V fp32 (50 MB) | xh/xl/xm (25 MB) | wh/wl/wm (19 MB)
    // aliases: attn_h/l over xh/xl (x dead after K1); oh/ol over wh/wl
    // (qkv_w splits dead after K1; out_w split launched after K1).
    char* base = (char*)d_ws;
    float* Q  = (float*)base;
    float* Kb = Q + (size_t)HBL * HD;
    float* V  = Kb + (size_t)HBL * HD;
    unsigned short* xh = (unsigned short*)(V + (size_t)HBL * HD);
    unsigned short* xl = xh + (size_t)MROWS * DDIM;
    unsigned short* xm = xl + (size_t)MROWS * DDIM;
    unsigned short* wh = xm + (size_t)MROWS * DDIM;
    unsigned short* wl = wh + (size_t)QKVN * DDIM;
    unsigned short* wm = wl + (size_t)QKVN * DDIM;
    unsigned short* attn_h = xh;
    unsigned short* attn_l = xl;
    unsigned short* oh = wh;
    unsigned short* ol = wl;

    // K0: 3-way splits for the QKV projection inputs
    split3_bf16<<<1024, 256, 0, stream>>>(x,     xh, xl, xm, MROWS * DDIM / 4);
    split3_bf16<<<1024, 256, 0, stream>>>(qkv_w, wh, wl, wm, QKVN * DDIM / 4);

    // K1: qkv = x @ qkv_w^T + qkv_b (6-product MFMA, fp32-exact), -> Q/K/V (H,B,L,64)
    gemm_bf16x3<true><<<dim3(QKVN / 128, MROWS / 128), 256, 0, stream>>>(
        xh, xl, xm, wh, wl, wm, qkv_b, Q, QKVN, DDIM);

    // K0b: out_w 2-way split (after K1; overwrites dead wh/wl region)
    split_bf16<<<512, 256, 0, stream>>>(out_w, oh, ol, DDIM * DDIM / 4);

    // K2: fused scores + topk + softmax + sparse PV -> attn (bf16 hi/lo over xh/xl)
    fused_attn<<<dim3(LSEQ / RPB, BATCH, H), 512, 0, stream>>>(Q, Kb, V, S, attn_h, attn_l);

    // K3: out = attn @ out_w^T + out_b (3-product MFMA)
    gemm_bf16x2<false><<<dim3(DDIM / 128, MROWS / 128), 256, 0, stream>>>(
        attn_h, attn_l, oh, ol, out_b, out, DDIM, DDIM);
}